// Round 1
// baseline (850.686 us; speedup 1.0000x reference)
//
#include <hip/hip_runtime.h>

typedef unsigned short u16;
typedef __attribute__((ext_vector_type(8))) short bf16x8;   // 8 bf16 in 4 VGPRs (per guide §3)
typedef __attribute__((ext_vector_type(4))) float f32x4;
typedef __attribute__((ext_vector_type(4))) unsigned int u32x4;
typedef __attribute__((ext_vector_type(2))) unsigned int u32x2;

#define MROWS 36      // 2 batches * 18 rows
#define SWZ(r,c) ((c) ^ (((r)&7)<<3))   // element-index XOR swizzle for 512B-stride bf16 LDS rows

__device__ inline u16 f2bf(float f){
  unsigned int u = __float_as_uint(f);
  return (u16)((u + 0x7fffu + ((u>>16)&1u)) >> 16);
}
__device__ inline unsigned int packbf(float a, float b){
  return (unsigned int)f2bf(a) | ((unsigned int)f2bf(b)<<16);
}
__device__ inline float bfloat_lo(unsigned int u){ return __uint_as_float(u<<16); }
__device__ inline float bfloat_hi(unsigned int u){ return __uint_as_float(u & 0xffff0000u); }
__device__ inline float bf2f(u16 h){ return __uint_as_float(((unsigned int)h)<<16); }
__device__ inline float wred(float v){
  #pragma unroll
  for (int m=1;m<64;m<<=1) v += __shfl_xor(v, m, 64);
  return v;
}
__device__ inline float silu_f(float x){ return x / (1.f + __expf(-x)); }
__device__ inline f32x4 mfma16(bf16x8 a, bf16x8 b, f32x4 c){
  return __builtin_amdgcn_mfma_f32_16x16x32_bf16(a, b, c, 0, 0, 0);
}

struct Params {
  const float *sigIn;
  const float *bn_g, *bn_b;
  const float *cWq,*cWk,*cWv,*cbq,*cbk,*cbv,*cbias_k,*cbias_v,*cWo,*cbo;
  const float *xbv, *xbias_v, *xbo;
  const float *b1,*b2,*b3;
  const float *g_cas,*b_cas,*g_ff,*b_ff,*g_fin,*b_fin;
  const u16 *Wv,*Wo,*Wq3,*W1b,*W2b,*W3p;
  const float *bias3, *ecr, *mu, *rstd;
  float *out;
};

// ---------------- prep: convert weights to bf16, build fused q-proj weights ----------------
__global__ void k_prep(const float* __restrict__ xWq, const float* __restrict__ xWk,
                       const float* __restrict__ xWv, const float* __restrict__ xWo,
                       const float* __restrict__ xbq, const float* __restrict__ xbk,
                       const float* __restrict__ xbias_k,
                       const float* __restrict__ W1, const float* __restrict__ W2,
                       const float* __restrict__ W3,
                       u16* Wv, u16* Wo, u16* Wq3, u16* W1b, u16* W2b, u16* W3p, float* bias3){
  const int gid = blockIdx.x*blockDim.x + threadIdx.x;
  const int gsz = gridDim.x*blockDim.x;
  for (int i=gid;i<65536;i+=gsz) Wv[i]=f2bf(xWv[i]);
  for (int i=gid;i<65536;i+=gsz) Wo[i]=f2bf(xWo[i]);
  for (int i=gid;i<8192;i+=gsz)  W1b[i]=f2bf(W1[i]);
  for (int i=gid;i<512;i+=gsz)   W2b[i]=f2bf(W2[i]);
  for (int i=gid;i<8192;i+=gsz){ int o=i>>5, k=i&31; W3p[i] = (k<16)? f2bf(W3[o*16+k]) : (u16)0; }
  for (int i=gid;i<8192;i+=gsz){           // Wq3[32][256]: rows 0-7 qw, 8-15 qb, 16-23 q2, 24-31 zero
    int r=i>>8, c=i&255;
    u16 outv = 0;
    if (r<24){
      int h=r&7, sel=r>>3;
      const float* vec = sel==0? xWk : (sel==1? xbk : xbias_k);
      float s=0.f;
      for (int d=0;d<32;++d) s += xWq[(size_t)(h*32+d)*256+c]*vec[h*32+d];
      outv = f2bf(s);
    }
    Wq3[i]=outv;
  }
  for (int i=gid;i<24;i+=gsz){
    int h=i&7, sel=i>>3;
    const float* vec = sel==0? xWk : (sel==1? xbk : xbias_k);
    float s=0.f; for (int d=0;d<32;++d) s += xbq[h*32+d]*vec[h*32+d];
    bias3[i]=s;
  }
}

// ---------------- ec_raw = ctx @ Ws^T + bs ----------------
__global__ void k_ec(const float* __restrict__ ctx, const float* __restrict__ Ws,
                     const float* __restrict__ bs, float* __restrict__ ecr){
  const int wave = threadIdx.x>>6, lane = threadIdx.x&63;
  const int b = blockIdx.x*4 + wave;
  const float* c = ctx + (size_t)b*512 + lane*8;
  const float4 a0 = *(const float4*)c, a1 = *(const float4*)(c+4);
  float cv[8] = {a0.x,a0.y,a0.z,a0.w,a1.x,a1.y,a1.z,a1.w};
  #pragma unroll 1
  for (int j=0;j<18;++j){
    const float* w = Ws + j*512 + lane*8;
    const float4 w0 = *(const float4*)w, w1 = *(const float4*)(w+4);
    float s = cv[0]*w0.x + cv[1]*w0.y + cv[2]*w0.z + cv[3]*w0.w
            + cv[4]*w1.x + cv[5]*w1.y + cv[6]*w1.z + cv[7]*w1.w;
    s = wred(s);
    if (lane==0) ecr[(size_t)b*18 + j] = s + bs[j];
  }
}

// ---------------- deterministic batch-norm stats over B=4096 ----------------
__global__ void k_bn(const float* __restrict__ ecr, float* __restrict__ mu, float* __restrict__ rstd){
  __shared__ float red[256];
  const int tid = threadIdx.x;
  for (int j=0;j<18;++j){
    float s=0.f, s2=0.f;
    for (int b=tid;b<4096;b+=256){ float v = ecr[(size_t)b*18+j]; s+=v; s2+=v*v; }
    red[tid]=s; __syncthreads();
    for (int o=128;o>0;o>>=1){ if(tid<o) red[tid]+=red[tid+o]; __syncthreads(); }
    float S = red[0]; __syncthreads();
    red[tid]=s2; __syncthreads();
    for (int o=128;o>0;o>>=1){ if(tid<o) red[tid]+=red[tid+o]; __syncthreads(); }
    float S2 = red[0]; __syncthreads();
    if (tid==0){ float m = S*(1.f/4096.f); float v = S2*(1.f/4096.f) - m*m;
                 mu[j]=m; rstd[j]=rsqrtf(v+1e-5f); }
  }
}

// ---------------- fused 4-layer decoder, 2 batches / block ----------------
__global__ __launch_bounds__(256, 2) void k_main(Params P){
  __shared__ __attribute__((aligned(16))) u16 s_sig[MROWS][256];  // residual stream, bf16, swizzled
  __shared__ __attribute__((aligned(16))) u16 s_ns [MROWS][256];  // ns / ca (shared), bf16, swizzled
  __shared__ __attribute__((aligned(16))) u16 s_v  [MROWS][256];  // v, bf16, swizzled
  __shared__ __attribute__((aligned(16))) u16 s_h1 [MROWS][32];   // FFN hidden (h1 then h2-padded)
  __shared__ float s_qq[MROWS][24];                               // qw | qb | q2 planes
  __shared__ float s_ec[2][18];

  const int tid  = threadIdx.x;
  const int wave = tid >> 6;
  const int lane = tid & 63;
  const int lr   = lane & 15;      // A-row / B-col within 16-tile
  const int lkg  = lane >> 4;      // k-group
  const int kof  = lkg * 8;
  const int dr   = lkg * 4;        // C/D row base: row=(lane>>4)*4+reg  (guide §3, HW-verified)
  const int b0   = blockIdx.x * 2;

  // ---- init: sig (f32 global -> bf16 LDS), ec (batch-norm applied)
  for (int idx = tid*8; idx < MROWS*256; idx += 256*8){
    const int row = idx >> 8, col = idx & 255;
    const float* src = P.sigIn + ((size_t)b0*18 + row)*256 + col;
    const float4 a = *(const float4*)src;
    const float4 b = *(const float4*)(src+4);
    u32x4 w;
    w[0]=packbf(a.x,a.y); w[1]=packbf(a.z,a.w);
    w[2]=packbf(b.x,b.y); w[3]=packbf(b.z,b.w);
    *(u32x4*)&s_sig[row][SWZ(row,col)] = w;
  }
  if (tid < 36){
    const int nb = tid/18, j = tid - nb*18;
    const float raw = P.ecr[(size_t)(b0+nb)*18 + j];
    s_ec[nb][j] = (raw - P.mu[j]) * P.rstd[j] * P.bn_g[j] + P.bn_b[j];
  }
  __syncthreads();

  auto ln_pass = [&](const float* g, const float* bvec){
    #pragma unroll 1
    for (int r = wave*9; r < wave*9+9; ++r){
      const int col = lane*4;
      const u32x2 raw = *(const u32x2*)&s_sig[r][SWZ(r,col)];
      const float x0 = bfloat_lo(raw[0]), x1 = bfloat_hi(raw[0]);
      const float x2 = bfloat_lo(raw[1]), x3 = bfloat_hi(raw[1]);
      const float m = wred(x0+x1+x2+x3)*(1.f/256.f);
      const float d0=x0-m, d1=x1-m, d2=x2-m, d3=x3-m;
      const float rs = rsqrtf(wred(d0*d0+d1*d1+d2*d2+d3*d3)*(1.f/256.f)+1e-10f);
      const float4 gv = *(const float4*)(g+col);
      const float4 bv = *(const float4*)(bvec+col);
      u32x2 o;
      o[0] = packbf(d0*rs*gv.x+bv.x, d1*rs*gv.y+bv.y);
      o[1] = packbf(d2*rs*gv.z+bv.z, d3*rs*gv.w+bv.w);
      *(u32x2*)&s_ns[r][SWZ(r,col)] = o;
    }
  };

  for (int layer = 0; layer < 4; ++layer){
    // ---- P0: context self-attention on ec (scalar, dim=1)
    float newec = 0.f;
    if (tid < 36){
      const int nb = tid/18, i = tid - nb*18;
      const float cwq=P.cWq[0], cbq=P.cbq[0], cwk=P.cWk[0], cbk=P.cbk[0];
      const float cwv=P.cWv[0], cbv=P.cbv[0], ck1=P.cbias_k[0], cv1=P.cbias_v[0];
      const float cwo=P.cWo[0], cbo=P.cbo[0];
      const float qi = s_ec[nb][i]*cwq + cbq;
      float sc[19]; float mx = -1e30f;
      #pragma unroll
      for (int j=0;j<18;++j){ sc[j] = qi*(s_ec[nb][j]*cwk + cbk); mx = fmaxf(mx, sc[j]); }
      sc[18] = qi*ck1; mx = fmaxf(mx, sc[18]);
      float den=0.f, o=0.f;
      #pragma unroll
      for (int j=0;j<18;++j){ const float pp=__expf(sc[j]-mx); den+=pp; o+=pp*(s_ec[nb][j]*cwv+cbv); }
      const float pp=__expf(sc[18]-mx); den+=pp; o+=pp*cv1;
      newec = s_ec[nb][i] + (o/den)*cwo + cbo;
    }
    __syncthreads();
    if (tid < 36){ const int nb = tid/18; s_ec[nb][tid - nb*18] = newec; }

    // ---- P1: ns = LN(sig) with ln_cas
    ln_pass(P.g_cas, P.b_cas);
    __syncthreads();

    // ---- P2+P3: fused q-proj (ns@Wq3^T) and v (ns@Wv^T + xbv)
    {
      f32x4 accV[3][4]; f32x4 accQ[3];
      #pragma unroll
      for (int mt=0;mt<3;++mt){
        accQ[mt] = f32x4{0.f,0.f,0.f,0.f};
        #pragma unroll
        for (int nt=0;nt<4;++nt) accV[mt][nt] = f32x4{0.f,0.f,0.f,0.f};
      }
      for (int kk=0; kk<8; ++kk){
        const int k0 = kk*32 + kof;
        bf16x8 afr[3];
        #pragma unroll
        for (int mt=0;mt<3;++mt){
          const int row = mt*16 + lr;
          u32x4 raw = u32x4{0u,0u,0u,0u};
          if (row < MROWS) raw = *(const u32x4*)&s_ns[row][SWZ(row,k0)];
          afr[mt] = __builtin_bit_cast(bf16x8, raw);
        }
        #pragma unroll
        for (int nt=0;nt<4;++nt){
          const int n = (wave*4+nt)*16 + lr;
          const bf16x8 bfr = __builtin_bit_cast(bf16x8, *(const u32x4*)(P.Wv + (size_t)n*256 + k0));
          #pragma unroll
          for (int mt=0;mt<3;++mt) accV[mt][nt] = mfma16(afr[mt], bfr, accV[mt][nt]);
        }
        if (wave < 2){
          const bf16x8 bq = __builtin_bit_cast(bf16x8, *(const u32x4*)(P.Wq3 + (size_t)(wave*16+lr)*256 + k0));
          #pragma unroll
          for (int mt=0;mt<3;++mt) accQ[mt] = mfma16(afr[mt], bq, accQ[mt]);
        }
      }
      #pragma unroll
      for (int nt=0;nt<4;++nt){
        const int n = (wave*4+nt)*16 + lr;
        const float bias = P.xbv[n];
        #pragma unroll
        for (int mt=0;mt<3;++mt){
          #pragma unroll
          for (int q=0;q<4;++q){
            const int row = mt*16 + dr + q;
            if (row < MROWS) s_v[row][SWZ(row,n)] = f2bf(accV[mt][nt][q] + bias);
          }
        }
      }
      if (wave < 2){
        const int c = wave*16 + lr;
        if (c < 24){
          const float bias = P.bias3[c];
          #pragma unroll
          for (int mt=0;mt<3;++mt){
            #pragma unroll
            for (int q=0;q<4;++q){
              const int row = mt*16 + dr + q;
              if (row < MROWS) s_qq[row][c] = accQ[mt][q] + bias;
            }
          }
        }
      }
    }
    __syncthreads();

    // ---- P4: attention (scores are rank-1 in position: ec[j]*qw + qb; softmax; ca = a@v)
    {
      const float scale = 0.17677669529663687f; // 1/sqrt(32)
      for (int t = tid; t < 288; t += 256){
        const int nb = t/144, rr = t - nb*144, h = rr/18, i = rr - h*18;
        const int qrow = nb*18 + i;
        const float qw = s_qq[qrow][h], qb = s_qq[qrow][8+h], q2v = s_qq[qrow][16+h];
        const float s18 = scale*q2v;
        float p[18]; float mx = s18;
        #pragma unroll
        for (int j=0;j<18;++j){ p[j] = scale*(s_ec[nb][j]*qw + qb); mx = fmaxf(mx, p[j]); }
        float den = 0.f;
        #pragma unroll
        for (int j=0;j<18;++j){ p[j] = __expf(p[j]-mx); den += p[j]; }
        const float p18 = __expf(s18-mx); den += p18;
        float acc[32];
        #pragma unroll
        for (int d4=0; d4<8; ++d4){
          const float4 xv = *(const float4*)(P.xbias_v + h*32 + d4*4);
          acc[d4*4+0]=p18*xv.x; acc[d4*4+1]=p18*xv.y; acc[d4*4+2]=p18*xv.z; acc[d4*4+3]=p18*xv.w;
        }
        #pragma unroll 1
        for (int j=0;j<18;++j){
          const float pj = p[j];
          const int vrow = nb*18 + j;
          #pragma unroll
          for (int d8=0; d8<4; ++d8){
            const u32x4 u = *(const u32x4*)&s_v[vrow][SWZ(vrow, h*32+d8*8)];
            #pragma unroll
            for (int q=0;q<4;++q){
              acc[d8*8+q*2]   += pj*bfloat_lo(u[q]);
              acc[d8*8+q*2+1] += pj*bfloat_hi(u[q]);
            }
          }
        }
        const float inv = 1.f/den;
        #pragma unroll
        for (int d8=0; d8<4; ++d8){
          u32x4 w;
          #pragma unroll
          for (int q=0;q<4;++q) w[q] = packbf(acc[d8*8+q*2]*inv, acc[d8*8+q*2+1]*inv);
          *(u32x4*)&s_ns[qrow][SWZ(qrow, h*32+d8*8)] = w;   // ca overwrites ns
        }
      }
    }
    __syncthreads();

    // ---- P5: sig += ca @ Wo^T + xbo
    {
      f32x4 acc[3][4];
      #pragma unroll
      for (int mt=0;mt<3;++mt){
        #pragma unroll
        for (int nt=0;nt<4;++nt) acc[mt][nt] = f32x4{0.f,0.f,0.f,0.f};
      }
      for (int kk=0; kk<8; ++kk){
        const int k0 = kk*32 + kof;
        bf16x8 afr[3];
        #pragma unroll
        for (int mt=0;mt<3;++mt){
          const int row = mt*16 + lr;
          u32x4 raw = u32x4{0u,0u,0u,0u};
          if (row < MROWS) raw = *(const u32x4*)&s_ns[row][SWZ(row,k0)];
          afr[mt] = __builtin_bit_cast(bf16x8, raw);
        }
        #pragma unroll
        for (int nt=0;nt<4;++nt){
          const int n = (wave*4+nt)*16 + lr;
          const bf16x8 bfr = __builtin_bit_cast(bf16x8, *(const u32x4*)(P.Wo + (size_t)n*256 + k0));
          #pragma unroll
          for (int mt=0;mt<3;++mt) acc[mt][nt] = mfma16(afr[mt], bfr, acc[mt][nt]);
        }
      }
      #pragma unroll
      for (int nt=0;nt<4;++nt){
        const int n = (wave*4+nt)*16 + lr;
        const float bias = P.xbo[n];
        #pragma unroll
        for (int mt=0;mt<3;++mt){
          #pragma unroll
          for (int q=0;q<4;++q){
            const int row = mt*16 + dr + q;
            if (row < MROWS){
              const int si = SWZ(row,n);
              s_sig[row][si] = f2bf(bf2f(s_sig[row][si]) + acc[mt][nt][q] + bias);
            }
          }
        }
      }
    }
    __syncthreads();

    // ---- P6: nf = LN(sig) with ln_ff
    ln_pass(P.g_ff, P.b_ff);
    __syncthreads();

    // ---- P7: h1 = silu(nf @ W1^T + b1)   (M x 32)
    if (wave < 2){
      f32x4 acc[3];
      #pragma unroll
      for (int mt=0;mt<3;++mt) acc[mt] = f32x4{0.f,0.f,0.f,0.f};
      for (int kk=0; kk<8; ++kk){
        const int k0 = kk*32 + kof;
        bf16x8 afr[3];
        #pragma unroll
        for (int mt=0;mt<3;++mt){
          const int row = mt*16 + lr;
          u32x4 raw = u32x4{0u,0u,0u,0u};
          if (row < MROWS) raw = *(const u32x4*)&s_ns[row][SWZ(row,k0)];
          afr[mt] = __builtin_bit_cast(bf16x8, raw);
        }
        const bf16x8 bfr = __builtin_bit_cast(bf16x8, *(const u32x4*)(P.W1b + (size_t)(wave*16+lr)*256 + k0));
        #pragma unroll
        for (int mt=0;mt<3;++mt) acc[mt] = mfma16(afr[mt], bfr, acc[mt]);
      }
      const int c = wave*16 + lr;
      const float bias = P.b1[c];
      #pragma unroll
      for (int mt=0;mt<3;++mt){
        #pragma unroll
        for (int q=0;q<4;++q){
          const int row = mt*16 + dr + q;
          if (row < MROWS) s_h1[row][c] = f2bf(silu_f(acc[mt][q] + bias));
        }
      }
    }
    __syncthreads();

    // ---- P8: h2 = silu(h1 @ W2^T + b2), written back into s_h1 with cols 16..31 zeroed (K-pad)
    if (wave < 3){
      const int row_a = wave*16 + lr;
      u32x4 raw = u32x4{0u,0u,0u,0u};
      if (row_a < MROWS) raw = *(const u32x4*)&s_h1[row_a][kof];
      const bf16x8 a = __builtin_bit_cast(bf16x8, raw);
      const bf16x8 b = __builtin_bit_cast(bf16x8, *(const u32x4*)(P.W2b + (size_t)lr*32 + kof));
      f32x4 acc = mfma16(a, b, f32x4{0.f,0.f,0.f,0.f});
      const float bias = P.b2[lr];
      #pragma unroll
      for (int q=0;q<4;++q){
        const int row = wave*16 + dr + q;
        if (row < MROWS){
          s_h1[row][lr]    = f2bf(silu_f(acc[q] + bias));
          s_h1[row][lr+16] = 0;
        }
      }
    }
    __syncthreads();

    // ---- P9: sig += silu(h2 @ W3p^T + b3)   (K=32 padded from 16)
    {
      bf16x8 afr[3];
      #pragma unroll
      for (int mt=0;mt<3;++mt){
        const int row = mt*16 + lr;
        u32x4 raw = u32x4{0u,0u,0u,0u};
        if (row < MROWS) raw = *(const u32x4*)&s_h1[row][kof];
        afr[mt] = __builtin_bit_cast(bf16x8, raw);
      }
      f32x4 acc[3][4];
      #pragma unroll
      for (int nt=0;nt<4;++nt){
        const int n = (wave*4+nt)*16 + lr;
        const bf16x8 bfr = __builtin_bit_cast(bf16x8, *(const u32x4*)(P.W3p + (size_t)n*32 + kof));
        #pragma unroll
        for (int mt=0;mt<3;++mt) acc[mt][nt] = mfma16(afr[mt], bfr, f32x4{0.f,0.f,0.f,0.f});
      }
      #pragma unroll
      for (int nt=0;nt<4;++nt){
        const int n = (wave*4+nt)*16 + lr;
        const float b3v = P.b3[n];
        #pragma unroll
        for (int mt=0;mt<3;++mt){
          #pragma unroll
          for (int q=0;q<4;++q){
            const int row = mt*16 + dr + q;
            if (row < MROWS){
              const int si = SWZ(row,n);
              s_sig[row][si] = f2bf(bf2f(s_sig[row][si]) + silu_f(acc[mt][nt][q] + b3v));
            }
          }
        }
      }
    }
    __syncthreads();
  } // layers

  // ---- final LN -> out (f32)
  {
    #pragma unroll 1
    for (int r = wave*9; r < wave*9+9; ++r){
      const int col = lane*4;
      const u32x2 raw = *(const u32x2*)&s_sig[r][SWZ(r,col)];
      const float x0 = bfloat_lo(raw[0]), x1 = bfloat_hi(raw[0]);
      const float x2 = bfloat_lo(raw[1]), x3 = bfloat_hi(raw[1]);
      const float m = wred(x0+x1+x2+x3)*(1.f/256.f);
      const float d0=x0-m, d1=x1-m, d2=x2-m, d3=x3-m;
      const float rs = rsqrtf(wred(d0*d0+d1*d1+d2*d2+d3*d3)*(1.f/256.f)+1e-10f);
      const float4 gv = *(const float4*)(P.g_fin+col);
      const float4 bv = *(const float4*)(P.b_fin+col);
      float4 o;
      o.x = d0*rs*gv.x+bv.x; o.y = d1*rs*gv.y+bv.y;
      o.z = d2*rs*gv.z+bv.z; o.w = d3*rs*gv.w+bv.w;
      *(float4*)(P.out + ((size_t)b0*18 + r)*256 + col) = o;
    }
  }
}

extern "C" void kernel_launch(void* const* d_in, const int* in_sizes, int n_in,
                              void* d_out, int out_size, void* d_ws, size_t ws_size,
                              hipStream_t stream) {
  (void)in_sizes; (void)n_in; (void)out_size; (void)ws_size;
  const float* sigIn   = (const float*)d_in[0];
  const float* ctx     = (const float*)d_in[1];
  const float* Ws      = (const float*)d_in[2];
  const float* bs      = (const float*)d_in[3];
  const float* bn_g    = (const float*)d_in[4];
  const float* bn_b    = (const float*)d_in[5];
  const float* cWq     = (const float*)d_in[6];
  const float* cWk     = (const float*)d_in[7];
  const float* cWv     = (const float*)d_in[8];
  const float* cbq     = (const float*)d_in[9];
  const float* cbk     = (const float*)d_in[10];
  const float* cbv     = (const float*)d_in[11];
  const float* cbias_k = (const float*)d_in[12];
  const float* cbias_v = (const float*)d_in[13];
  const float* cWo     = (const float*)d_in[14];
  const float* cbo     = (const float*)d_in[15];
  const float* xWq     = (const float*)d_in[16];
  const float* xWk     = (const float*)d_in[17];
  const float* xWv     = (const float*)d_in[18];
  const float* xbq     = (const float*)d_in[19];
  const float* xbk     = (const float*)d_in[20];
  const float* xbv     = (const float*)d_in[21];
  const float* xbias_k = (const float*)d_in[22];
  const float* xbias_v = (const float*)d_in[23];
  const float* xWo     = (const float*)d_in[24];
  const float* xbo     = (const float*)d_in[25];
  const float* W1      = (const float*)d_in[26];
  const float* b1      = (const float*)d_in[27];
  const float* W2      = (const float*)d_in[28];
  const float* b2      = (const float*)d_in[29];
  const float* W3      = (const float*)d_in[30];
  const float* b3      = (const float*)d_in[31];
  const float* g_ff    = (const float*)d_in[32];
  const float* b_ff    = (const float*)d_in[33];
  const float* g_cas   = (const float*)d_in[34];
  const float* b_cas   = (const float*)d_in[35];
  const float* g_fin   = (const float*)d_in[36];
  const float* b_fin   = (const float*)d_in[37];

  char* ws = (char*)d_ws;
  u16*  Wv    = (u16*)(ws);             // 131072 B
  u16*  Wo    = (u16*)(ws + 131072);    // 131072 B
  u16*  Wq3   = (u16*)(ws + 262144);    // 16384 B
  u16*  W1b   = (u16*)(ws + 278528);    // 16384 B
  u16*  W2b   = (u16*)(ws + 294912);    // 1024 B
  u16*  W3p   = (u16*)(ws + 295936);    // 16384 B
  float* bias3= (float*)(ws + 312320);  // 96 B (pad to 128)
  float* ecr  = (float*)(ws + 312448);  // 294912 B
  float* mu   = (float*)(ws + 607360);  // 72 B (pad)
  float* rstd = (float*)(ws + 607488);  // 72 B

  k_prep<<<dim3(64), dim3(256), 0, stream>>>(xWq, xWk, xWv, xWo, xbq, xbk, xbias_k,
                                             W1, W2, W3, Wv, Wo, Wq3, W1b, W2b, W3p, bias3);
  k_ec<<<dim3(1024), dim3(256), 0, stream>>>(ctx, Ws, bs, ecr);
  k_bn<<<dim3(1), dim3(256), 0, stream>>>(ecr, mu, rstd);

  Params P;
  P.sigIn = sigIn; P.bn_g = bn_g; P.bn_b = bn_b;
  P.cWq=cWq; P.cWk=cWk; P.cWv=cWv; P.cbq=cbq; P.cbk=cbk; P.cbv=cbv;
  P.cbias_k=cbias_k; P.cbias_v=cbias_v; P.cWo=cWo; P.cbo=cbo;
  P.xbv=xbv; P.xbias_v=xbias_v; P.xbo=xbo;
  P.b1=b1; P.b2=b2; P.b3=b3;
  P.g_cas=g_cas; P.b_cas=b_cas; P.g_ff=g_ff; P.b_ff=b_ff; P.g_fin=g_fin; P.b_fin=b_fin;
  P.Wv=Wv; P.Wo=Wo; P.Wq3=Wq3; P.W1b=W1b; P.W2b=W2b; P.W3p=W3p;
  P.bias3=bias3; P.ecr=ecr; P.mu=mu; P.rstd=rstd;
  P.out = (float*)d_out;

  k_main<<<dim3(2048), dim3(256), 0, stream>>>(P);
}